// Round 9
// baseline (206.386 us; speedup 1.0000x reference)
//
#include <hip/hip_runtime.h>
#include <stdint.h>

#define NB 8
#define CC 512
#define PP 2304
#define EPSF 1e-5f
#define RCH 12

typedef short bf16x8 __attribute__((ext_vector_type(8)));
typedef float f32x4 __attribute__((ext_vector_type(4)));

typedef __attribute__((address_space(3))) uint8_t lds8_t;
typedef __attribute__((address_space(1))) const uint8_t g8_t;

__device__ __forceinline__ void async16(void* lds, const void* g) {
  __builtin_amdgcn_global_load_lds((g8_t*)g, (lds8_t*)lds, 16, 0, 0);
}

__device__ __forceinline__ float bf2lo(uint32_t u) { return __uint_as_float(u << 16); }
__device__ __forceinline__ float bf2hi(uint32_t u) { return __uint_as_float(u & 0xffff0000u); }
__device__ __forceinline__ uint32_t f2bf(float f) {  // RNE
  uint32_t u = __float_as_uint(f);
  return (u + 0x7fffu + ((u >> 16) & 1u)) >> 16;
}

template <int N>
__device__ __forceinline__ void vmwait() {
  if constexpr (N == 0) asm volatile("s_waitcnt vmcnt(0)" ::: "memory");
  else if constexpr (N == 4) asm volatile("s_waitcnt vmcnt(4)" ::: "memory");
  else if constexpr (N == 6) asm volatile("s_waitcnt vmcnt(6)" ::: "memory");
  else if constexpr (N == 8) asm volatile("s_waitcnt vmcnt(8)" ::: "memory");
  // N < 0: no wait
}

// ------- K1: cast bf16 (UNcentered), transpose [N][C][P]->[N][P][C], raw sumsq,
//         + channel sums of target (reusing the lt transpose tile) -------
__global__ __launch_bounds__(256) void k_cast(
    const float* __restrict__ pred, const float* __restrict__ tgt,
    uint16_t* __restrict__ xt, uint16_t* __restrict__ yt,
    float* __restrict__ ssx, float* __restrict__ ssy, float* __restrict__ musum) {
  __shared__ uint32_t lt[64][33];   // [p][c-pair], +1 pad -> conflict-free
  __shared__ float red[4][64];
  const int p0 = blockIdx.x * 64, c0 = blockIdx.y * 64, n = blockIdx.z;
  const int t = threadIdx.x, lp = t & 63, cb = t >> 6;
  for (int which = 0; which < 2; ++which) {
    const float* in = which ? tgt : pred;
    uint16_t* out = which ? yt : xt;
    float* ss = which ? ssy : ssx;
    float sq = 0.f;
    uint32_t packs[8];
#pragma unroll
    for (int i = 0; i < 16; ++i) {
      const int c = c0 + cb * 16 + i;
      float v = in[((size_t)n * CC + c) * PP + p0 + lp];
      sq += v * v;
      uint32_t b = f2bf(v);
      if (i & 1) packs[i >> 1] |= b << 16; else packs[i >> 1] = b;
    }
#pragma unroll
    for (int j = 0; j < 8; ++j) lt[lp][cb * 8 + j] = packs[j];
    red[cb][lp] = sq;
    __syncthreads();
    if (t < 64)
      atomicAdd(&ss[(size_t)n * PP + p0 + t],
                red[0][t] + red[1][t] + red[2][t] + red[3][t]);
    if (which && t < 32) {  // channel sums over this block's 64 p's (bf16 values)
      float s0 = 0.f, s1 = 0.f;
      for (int p = 0; p < 64; ++p) {   // lt[p][t]: bank (p+t)%32 -> conflict-free
        const uint32_t u = lt[p][t];
        s0 += bf2lo(u); s1 += bf2hi(u);
      }
      atomicAdd(&musum[c0 + 2 * t], s0);
      atomicAdd(&musum[c0 + 2 * t + 1], s1);
    }
    const int p = t >> 2, ch = t & 3;
    uint4 v0, v1;
    v0.x = lt[p][ch * 8 + 0]; v0.y = lt[p][ch * 8 + 1];
    v0.z = lt[p][ch * 8 + 2]; v0.w = lt[p][ch * 8 + 3];
    v1.x = lt[p][ch * 8 + 4]; v1.y = lt[p][ch * 8 + 5];
    v1.z = lt[p][ch * 8 + 6]; v1.w = lt[p][ch * 8 + 7];
    uint4* ob = (uint4*)(out + (((size_t)n * PP + p0 + p) * CC + c0 + ch * 16));
    ob[0] = v0; ob[1] = v1;
    __syncthreads();
  }
}

// ------- K2: mv'[r] = mu . row_r - ||mu||^2/2  (mu = musum/18432) -------
__global__ __launch_bounds__(256) void k_gemv(
    const float* __restrict__ musum,
    const uint16_t* __restrict__ xt, const uint16_t* __restrict__ yt,
    float* __restrict__ mvx, float* __restrict__ mvy) {
  const uint16_t* T = blockIdx.y ? yt : xt;
  float* mv = blockIdx.y ? mvy : mvx;
  __shared__ float mu_l[512];
  __shared__ float m2red[4];
  const int t = threadIdx.x, w = t >> 6, lane = t & 63;
  const float scale = 1.0f / (NB * PP);
  float m2p = 0.f;
  for (int i = t; i < 512; i += 256) {
    float m = musum[i] * scale;
    mu_l[i] = m;
    m2p += m * m;
  }
#pragma unroll
  for (int d = 1; d < 64; d <<= 1) m2p += __shfl_xor(m2p, d);
  if (lane == 0) m2red[w] = m2p;
  __syncthreads();
  const float mu2h = 0.5f * (m2red[0] + m2red[1] + m2red[2] + m2red[3]);
  for (int it = 0; it < 16; ++it) {
    const int r = blockIdx.x * 64 + w * 16 + it;
    uint4 u = *(const uint4*)(T + (size_t)r * CC + lane * 8);
    float s = 0.f;
    const float* m = &mu_l[lane * 8];
    s += bf2lo(u.x) * m[0] + bf2hi(u.x) * m[1];
    s += bf2lo(u.y) * m[2] + bf2hi(u.y) * m[3];
    s += bf2lo(u.z) * m[4] + bf2hi(u.z) * m[5];
    s += bf2lo(u.w) * m[6] + bf2hi(u.w) * m[7];
#pragma unroll
    for (int d = 1; d < 64; d <<= 1) s += __shfl_xor(s, d);
    if (lane == 0) mv[r] = s - mu2h;
  }
}

// ---------------- K3: 256x256-tile 8-phase GEMM (round-3 measured-best schedule) ----------------
__device__ __forceinline__ void stage_half(uint16_t* dst, const uint16_t* g, int tid) {
  async16((char*)dst + tid * 16, g);
  async16((char*)dst + tid * 16 + 8192, g + 64 * CC);
}

template <int QM, int QN, bool LA, bool STG, int VM>
__device__ __forceinline__ void phase(const uint16_t (*R)[8192],
                                      uint16_t* sdst, const uint16_t* ssrc,
                                      int tid, int lane, int wr, int wcn,
                                      bf16x8 (&af)[4][2], f32x4 (&acc)[2][4][2][2]) {
  if (LA) {
#pragma unroll
    for (int i = 0; i < 4; ++i) {
      const int rh = wr * 64 + i * 16 + (lane & 15);
      const char* base = (const char*)R[QM] + rh * 128;
      const int sw = (rh & 7) << 4;
#pragma unroll
      for (int kk = 0; kk < 2; ++kk)
        af[i][kk] = *(const bf16x8*)(base + ((kk * 64 + (lane >> 4) * 16) ^ sw));
    }
  }
  bf16x8 bfv[2][2];
#pragma unroll
  for (int j = 0; j < 2; ++j) {
    const int rh = wcn * 32 + j * 16 + (lane & 15);
    const char* base = (const char*)R[2 + QN] + rh * 128;
    const int sw = (rh & 7) << 4;
#pragma unroll
    for (int kk = 0; kk < 2; ++kk)
      bfv[j][kk] = *(const bf16x8*)(base + ((kk * 64 + (lane >> 4) * 16) ^ sw));
  }
  if (STG) stage_half(sdst, ssrc, tid);
  __builtin_amdgcn_s_barrier();
  asm volatile("s_waitcnt lgkmcnt(0)" ::: "memory");
  __builtin_amdgcn_s_setprio(1);
#pragma unroll
  for (int i = 0; i < 4; ++i)
#pragma unroll
    for (int j = 0; j < 2; ++j)
#pragma unroll
      for (int kk = 0; kk < 2; ++kk)
        acc[QM][i][QN][j] = __builtin_amdgcn_mfma_f32_16x16x32_bf16(
            af[i][kk], bfv[j][kk], acc[QM][i][QN][j], 0, 0, 0);
  __builtin_amdgcn_s_setprio(0);
  vmwait<VM>();
  __builtin_amdgcn_s_barrier();
}

__global__ __launch_bounds__(512, 2) void k_gemm(
    const uint16_t* __restrict__ xt, const uint16_t* __restrict__ yt,
    const float* __restrict__ ssx, const float* __restrict__ ssy,
    const float* __restrict__ mvx, const float* __restrict__ mvy,
    uint16_t* __restrict__ S) {
  __shared__ uint16_t lds[2][4][8192];  // 128 KiB
  int flat = blockIdx.x + 9 * blockIdx.y + 81 * blockIdx.z;
  flat = (flat & 7) * 81 + (flat >> 3);  // 648 = 8*81 -> bijective XCD swizzle
  const int nb = flat / 81;
  const int rem = flat - nb * 81;
  const int m0 = (rem % 9) * 256, n0 = (rem / 9) * 256;
  const int tid = threadIdx.x, lane = tid & 63, wid = tid >> 6;
  const int wr = wid >> 2, wcn = wid & 3;
  const uint16_t* Ax = xt + (size_t)nb * PP * CC;
  const uint16_t* By = yt + (size_t)nb * PP * CC;
  const int lswz = (tid & 7) ^ ((tid >> 3) & 7);
  const uint16_t* gAb = Ax + (size_t)(m0 + (tid >> 3)) * CC + lswz * 8;
  const uint16_t* gBb = By + (size_t)(n0 + (tid >> 3)) * CC + lswz * 8;

  f32x4 acc[2][4][2][2];
#pragma unroll
  for (int a = 0; a < 2; ++a)
#pragma unroll
    for (int b = 0; b < 4; ++b)
#pragma unroll
      for (int c = 0; c < 2; ++c)
#pragma unroll
        for (int d = 0; d < 2; ++d) acc[a][b][c][d] = (f32x4){0.f, 0.f, 0.f, 0.f};

  // prologue: as-if ph3,4(kt-2), ph1,2(kt-1), ph3,4(kt-1)
  stage_half(lds[0][0], gAb, tid);              // A0(0)
  stage_half(lds[0][2], gBb, tid);              // B0(0)
  stage_half(lds[0][1], gAb + 128 * CC, tid);   // A1(0)
  stage_half(lds[0][3], gBb + 128 * CC, tid);   // B1(0)
  stage_half(lds[1][0], gAb + 64, tid);         // A0(1)
  stage_half(lds[1][2], gBb + 64, tid);         // B0(1)
  vmwait<8>();                                   // A0(0),B0(0) resident
  __builtin_amdgcn_s_barrier();

  bf16x8 af[4][2];
  for (int kt = 0; kt < 6; ++kt) {
    const int cur = kt & 1;
    const uint16_t(*R)[8192] = lds[cur];
    uint16_t(*Wn)[8192] = lds[cur ^ 1];
    uint16_t(*Wc)[8192] = lds[cur];
    const int ko = (kt + 1) * 64;
    // ph1(0,0): stage A1(kt+1); vmcnt(6) guards this tile's A1/B1
    phase<0, 0, true, true, 6>(R, Wn[1], gAb + 128 * CC + ko, tid, lane, wr, wcn, af, acc);
    // ph2(0,1): stage B1(kt+1)
    phase<0, 1, false, true, -1>(R, Wn[3], gBb + 128 * CC + ko, tid, lane, wr, wcn, af, acc);
    // ph3(1,0): stage A0(kt+2) into freed A0 of current buf
    phase<1, 0, true, true, -1>(R, Wc[0], gAb + ko + 64, tid, lane, wr, wcn, af, acc);
    // ph4(1,1): stage B0(kt+2); vmcnt(8) guards next tile's A0,B0
    phase<1, 1, false, true, 8>(R, Wc[2], gBb + ko + 64, tid, lane, wr, wcn, af, acc);
  }
  {  // kt = 6 (cur = 0): last A1/B1 stages; drain ramps 8->4
    const uint16_t(*R)[8192] = lds[0];
    phase<0, 0, true, true, 6>(R, lds[1][1], gAb + 128 * CC + 7 * 64, tid, lane, wr, wcn, af, acc);
    phase<0, 1, false, true, -1>(R, lds[1][3], gBb + 128 * CC + 7 * 64, tid, lane, wr, wcn, af, acc);
    phase<1, 0, true, false, -1>(R, nullptr, nullptr, tid, lane, wr, wcn, af, acc);
    phase<1, 1, false, false, 4>(R, nullptr, nullptr, tid, lane, wr, wcn, af, acc);
  }
  {  // kt = 7 (cur = 1): final tile, drain to 0 after ph1
    const uint16_t(*R)[8192] = lds[1];
    phase<0, 0, true, false, 0>(R, nullptr, nullptr, tid, lane, wr, wcn, af, acc);
    phase<0, 1, false, false, -1>(R, nullptr, nullptr, tid, lane, wr, wcn, af, acc);
    phase<1, 0, true, false, -1>(R, nullptr, nullptr, tid, lane, wr, wcn, af, acc);
    phase<1, 1, false, false, -1>(R, nullptr, nullptr, tid, lane, wr, wcn, af, acc);
  }

  // epilogue: centering corrections + inverse norms, write bf16 cosine
  const float* rsp = ssx + (size_t)nb * PP + m0;
  const float* csp = ssy + (size_t)nb * PP + n0;
  const float* mvr = mvx + (size_t)nb * PP + m0;
  const float* mvc = mvy + (size_t)nb * PP + n0;
  uint16_t* Sp = S + (size_t)nb * PP * PP;
  float cinv[2][2], cmv[2][2];
#pragma unroll
  for (int qn = 0; qn < 2; ++qn)
#pragma unroll
    for (int j = 0; j < 2; ++j) {
      const int col = qn * 128 + wcn * 32 + j * 16 + (lane & 15);
      const float m = mvc[col];
      cmv[qn][j] = m;
      cinv[qn][j] = 1.0f / fmaxf(sqrtf(csp[col] - 2.0f * m), 1e-12f);
    }
#pragma unroll
  for (int qm = 0; qm < 2; ++qm)
#pragma unroll
    for (int i = 0; i < 4; ++i)
#pragma unroll
      for (int r = 0; r < 4; ++r) {
        const int row = qm * 128 + wr * 64 + i * 16 + (lane >> 4) * 4 + r;
        const float mr = mvr[row];
        const float rinv = 1.0f / fmaxf(sqrtf(rsp[row] - 2.0f * mr), 1e-12f);
        uint16_t* orow = Sp + (size_t)(m0 + row) * PP + n0;
#pragma unroll
        for (int qn = 0; qn < 2; ++qn)
#pragma unroll
          for (int j = 0; j < 2; ++j)
            orow[qn * 128 + wcn * 32 + j * 16 + (lane & 15)] = (uint16_t)f2bf(
                (acc[qm][i][qn][j][r] - mr - cmv[qn][j]) * rinv * cinv[qn][j]);
      }
}

// ------- K4: fused row-stats + colmax (w=exp in LDS bf16) + last-block final loss -------
__global__ __launch_bounds__(256) void k_rowcol(const uint16_t* __restrict__ S,
                                                int* __restrict__ cxcol,
                                                int* __restrict__ done,
                                                float* __restrict__ out) {
  const int pc = blockIdx.x, n = blockIdx.y;  // 24-row chunk, as 2x12-row LDS passes
  __shared__ uint16_t wlds[RCH][PP];          // 55296 B of bf16 w-values
  __shared__ float lri[RCH];
  __shared__ float redf[4];
  __shared__ int lastf;
  const int t = threadIdx.x, w = t >> 6, lane = t & 63;
  const size_t Sn = (size_t)n * PP * PP + (size_t)pc * 24 * PP;
  float best0[5], best1[5];
#pragma unroll
  for (int i = 0; i < 5; ++i) { best0[i] = 0.f; best1[i] = 0.f; }
  for (int half = 0; half < 2; ++half) {
    // pass 1: 4 waves x 3 rows; row in-register; w -> LDS bf16; rowsum in f32
    for (int it = 0; it < 3; ++it) {
      const int r = w * 3 + it;  // 0..11
      const uint2* rp = (const uint2*)(S + Sn + (size_t)(half * RCH + r) * PP);
      uint2 u[9];
#pragma unroll
      for (int k = 0; k < 9; ++k) u[k] = rp[lane + k * 64];
      float v[36];
#pragma unroll
      for (int k = 0; k < 9; ++k) {
        v[4 * k + 0] = bf2lo(u[k].x); v[4 * k + 1] = bf2hi(u[k].x);
        v[4 * k + 2] = bf2lo(u[k].y); v[4 * k + 3] = bf2hi(u[k].y);
      }
      float mx = v[0];
#pragma unroll
      for (int k = 1; k < 36; ++k) mx = fmaxf(mx, v[k]);
#pragma unroll
      for (int d = 1; d < 64; d <<= 1) mx = fmaxf(mx, __shfl_xor(mx, d));
      const float sc = 2.0f / (1.0f - mx + EPSF);
      const float b = (EPSF - mx) * sc;
      float s = 0.f;
#pragma unroll
      for (int k = 0; k < 9; ++k) {
        const float w0 = __expf(fmaf(v[4 * k + 0], sc, b));
        const float w1 = __expf(fmaf(v[4 * k + 1], sc, b));
        const float w2 = __expf(fmaf(v[4 * k + 2], sc, b));
        const float w3 = __expf(fmaf(v[4 * k + 3], sc, b));
        s += (w0 + w1) + (w2 + w3);
        uint2 wp;
        wp.x = f2bf(w0) | (f2bf(w1) << 16);
        wp.y = f2bf(w2) | (f2bf(w3) << 16);
        ((uint2*)&wlds[r][0])[lane + k * 64] = wp;
      }
#pragma unroll
      for (int d = 1; d < 64; d <<= 1) s += __shfl_xor(s, d);
      if (lane == 0) lri[r] = 1.0f / s;
    }
    __syncthreads();
    // pass 2: colmax from LDS (mul+max only, no exp); fixed 5-iter for static reg idx
#pragma unroll
    for (int i = 0; i < 5; ++i) {
      const int pi = t + i * 256;
      if (pi < PP / 2) {
        float b0 = best0[i], b1 = best1[i];
#pragma unroll
        for (int r = 0; r < RCH; ++r) {
          const uint32_t u = ((const uint32_t*)&wlds[r][0])[pi];
          const float ri = lri[r];
          b0 = fmaxf(b0, bf2lo(u) * ri);
          b1 = fmaxf(b1, bf2hi(u) * ri);
        }
        best0[i] = b0; best1[i] = b1;
      }
    }
    __syncthreads();  // LDS reuse guard
  }
#pragma unroll
  for (int i = 0; i < 5; ++i) {
    const int pi = t + i * 256;
    if (pi < PP / 2) {
      atomicMax(&cxcol[n * PP + 2 * pi], __float_as_int(best0[i]));
      atomicMax(&cxcol[n * PP + 2 * pi + 1], __float_as_int(best1[i]));
    }
  }
  // ---- completion: last block computes the final loss ----
  __threadfence();
  __syncthreads();
  if (t == 0) lastf = (atomicAdd(done, 1) == 96 * NB - 1);
  __syncthreads();
  if (!lastf) return;
  __threadfence();  // acquire: all cxcol atomicMax results visible
  float a = 0.f;
  for (int nn = 0; nn < NB; ++nn) {
    float s = 0.f;
    for (int q = t; q < PP; q += 256) s += __int_as_float(cxcol[nn * PP + q]);
#pragma unroll
    for (int d = 1; d < 64; d <<= 1) s += __shfl_xor(s, d);
    if (lane == 0) redf[w] = s;
    __syncthreads();
    if (t == 0) a += -logf((redf[0] + redf[1] + redf[2] + redf[3]) * (1.0f / PP) + EPSF);
    __syncthreads();
  }
  if (t == 0) out[0] = a * (1.0f / NB);
}

extern "C" void kernel_launch(void* const* d_in, const int* in_sizes, int n_in,
                              void* d_out, int out_size, void* d_ws, size_t ws_size,
                              hipStream_t stream) {
  const float* pred = (const float*)d_in[0];
  const float* tgt  = (const float*)d_in[1];
  float* W = (float*)d_ws;
  // workspace layout (float indices)
  float* musum = W + 0;              // 512
  float* ssx   = W + 512;            // 18432
  float* ssy   = W + 18944;          // 18432
  int*   cxcol = (int*)(W + 37376);  // 18432
  int*   done  = (int*)(W + 55808);  // 1
  float* mvx   = W + 56320;          // 18432
  float* mvy   = W + 74752;          // 18432
  uint16_t* xt = (uint16_t*)(W + 93440);        // 9437184 bf16
  uint16_t* yt = xt + (size_t)NB * PP * CC;     // 9437184 bf16
  uint16_t* S  = yt + (size_t)NB * PP * CC;     // 42467328 bf16

  // zero: musum, ssx, ssy, cxcol (0x0 = 0.0f; all cx values > 0), done
  hipMemsetAsync(W, 0, 55812 * sizeof(float), stream);

  k_cast<<<dim3(PP / 64, CC / 64, NB), dim3(256), 0, stream>>>(
      pred, tgt, xt, yt, ssx, ssy, musum);
  k_gemv<<<dim3(288, 2), dim3(256), 0, stream>>>(musum, xt, yt, mvx, mvy);
  k_gemm<<<dim3(9, 9, NB), dim3(512), 0, stream>>>(xt, yt, ssx, ssy, mvx, mvy, S);
  k_rowcol<<<dim3(96, NB), dim3(256), 0, stream>>>(S, cxcol, done, (float*)d_out);
}

// Round 10
// 157.629 us; speedup vs baseline: 1.3093x; 1.3093x over previous
//
#include <hip/hip_runtime.h>
#include <stdint.h>

#define NB 8
#define CC 512
#define PP 2304
#define EPSF 1e-5f
#define RCH 12

typedef short bf16x8 __attribute__((ext_vector_type(8)));
typedef float f32x4 __attribute__((ext_vector_type(4)));

typedef __attribute__((address_space(3))) uint8_t lds8_t;
typedef __attribute__((address_space(1))) const uint8_t g8_t;

__device__ __forceinline__ void async16(void* lds, const void* g) {
  __builtin_amdgcn_global_load_lds((g8_t*)g, (lds8_t*)lds, 16, 0, 0);
}

__device__ __forceinline__ float bf2lo(uint32_t u) { return __uint_as_float(u << 16); }
__device__ __forceinline__ float bf2hi(uint32_t u) { return __uint_as_float(u & 0xffff0000u); }
__device__ __forceinline__ uint32_t f2bf(float f) {  // RNE
  uint32_t u = __float_as_uint(f);
  return (u + 0x7fffu + ((u >> 16) & 1u)) >> 16;
}

template <int N>
__device__ __forceinline__ void vmwait() {
  if constexpr (N == 0) asm volatile("s_waitcnt vmcnt(0)" ::: "memory");
  else if constexpr (N == 4) asm volatile("s_waitcnt vmcnt(4)" ::: "memory");
  else if constexpr (N == 6) asm volatile("s_waitcnt vmcnt(6)" ::: "memory");
  else if constexpr (N == 8) asm volatile("s_waitcnt vmcnt(8)" ::: "memory");
  // N < 0: no wait
}

// ------- K1: cast bf16 (UNcentered), transpose [N][C][P]->[N][P][C], raw sumsq,
//         + channel sums of target (reusing the lt transpose tile) -------
__global__ __launch_bounds__(256) void k_cast(
    const float* __restrict__ pred, const float* __restrict__ tgt,
    uint16_t* __restrict__ xt, uint16_t* __restrict__ yt,
    float* __restrict__ ssx, float* __restrict__ ssy, float* __restrict__ musum) {
  __shared__ uint32_t lt[64][33];   // [p][c-pair], +1 pad -> conflict-free
  __shared__ float red[4][64];
  const int p0 = blockIdx.x * 64, c0 = blockIdx.y * 64, n = blockIdx.z;
  const int t = threadIdx.x, lp = t & 63, cb = t >> 6;
  for (int which = 0; which < 2; ++which) {
    const float* in = which ? tgt : pred;
    uint16_t* out = which ? yt : xt;
    float* ss = which ? ssy : ssx;
    float sq = 0.f;
    uint32_t packs[8];
#pragma unroll
    for (int i = 0; i < 16; ++i) {
      const int c = c0 + cb * 16 + i;
      float v = in[((size_t)n * CC + c) * PP + p0 + lp];
      sq += v * v;
      uint32_t b = f2bf(v);
      if (i & 1) packs[i >> 1] |= b << 16; else packs[i >> 1] = b;
    }
#pragma unroll
    for (int j = 0; j < 8; ++j) lt[lp][cb * 8 + j] = packs[j];
    red[cb][lp] = sq;
    __syncthreads();
    if (t < 64)
      atomicAdd(&ss[(size_t)n * PP + p0 + t],
                red[0][t] + red[1][t] + red[2][t] + red[3][t]);
    if (which && t < 32) {  // channel sums over this block's 64 p's (bf16 values)
      float s0 = 0.f, s1 = 0.f;
      for (int p = 0; p < 64; ++p) {   // lt[p][t]: bank (p+t)%32 -> conflict-free
        const uint32_t u = lt[p][t];
        s0 += bf2lo(u); s1 += bf2hi(u);
      }
      atomicAdd(&musum[c0 + 2 * t], s0);
      atomicAdd(&musum[c0 + 2 * t + 1], s1);
    }
    const int p = t >> 2, ch = t & 3;
    uint4 v0, v1;
    v0.x = lt[p][ch * 8 + 0]; v0.y = lt[p][ch * 8 + 1];
    v0.z = lt[p][ch * 8 + 2]; v0.w = lt[p][ch * 8 + 3];
    v1.x = lt[p][ch * 8 + 4]; v1.y = lt[p][ch * 8 + 5];
    v1.z = lt[p][ch * 8 + 6]; v1.w = lt[p][ch * 8 + 7];
    uint4* ob = (uint4*)(out + (((size_t)n * PP + p0 + p) * CC + c0 + ch * 16));
    ob[0] = v0; ob[1] = v1;
    __syncthreads();
  }
}

// ------- K2: mv'[r] = mu . row_r - ||mu||^2/2  (mu = musum/18432) -------
__global__ __launch_bounds__(256) void k_gemv(
    const float* __restrict__ musum,
    const uint16_t* __restrict__ xt, const uint16_t* __restrict__ yt,
    float* __restrict__ mvx, float* __restrict__ mvy) {
  const uint16_t* T = blockIdx.y ? yt : xt;
  float* mv = blockIdx.y ? mvy : mvx;
  __shared__ float mu_l[512];
  __shared__ float m2red[4];
  const int t = threadIdx.x, w = t >> 6, lane = t & 63;
  const float scale = 1.0f / (NB * PP);
  float m2p = 0.f;
  for (int i = t; i < 512; i += 256) {
    float m = musum[i] * scale;
    mu_l[i] = m;
    m2p += m * m;
  }
#pragma unroll
  for (int d = 1; d < 64; d <<= 1) m2p += __shfl_xor(m2p, d);
  if (lane == 0) m2red[w] = m2p;
  __syncthreads();
  const float mu2h = 0.5f * (m2red[0] + m2red[1] + m2red[2] + m2red[3]);
  for (int it = 0; it < 16; ++it) {
    const int r = blockIdx.x * 64 + w * 16 + it;
    uint4 u = *(const uint4*)(T + (size_t)r * CC + lane * 8);
    float s = 0.f;
    const float* m = &mu_l[lane * 8];
    s += bf2lo(u.x) * m[0] + bf2hi(u.x) * m[1];
    s += bf2lo(u.y) * m[2] + bf2hi(u.y) * m[3];
    s += bf2lo(u.z) * m[4] + bf2hi(u.z) * m[5];
    s += bf2lo(u.w) * m[6] + bf2hi(u.w) * m[7];
#pragma unroll
    for (int d = 1; d < 64; d <<= 1) s += __shfl_xor(s, d);
    if (lane == 0) mv[r] = s - mu2h;
  }
}

// ---------------- K3: 256x256-tile 8-phase GEMM (round-3 schedule + B-frag reg caching) ----------------
__device__ __forceinline__ void stage_half(uint16_t* dst, const uint16_t* g, int tid) {
  async16((char*)dst + tid * 16, g);
  async16((char*)dst + tid * 16 + 8192, g + 64 * CC);
}

// LA: load A-quadrant QM into af; LB: load B-quadrant QN into bf[QN] (else use cached).
template <int QM, int QN, bool LA, bool LB, bool STG, int VM>
__device__ __forceinline__ void phase(const uint16_t (*R)[8192],
                                      uint16_t* sdst, const uint16_t* ssrc,
                                      int tid, int lane, int wr, int wcn,
                                      bf16x8 (&af)[4][2], bf16x8 (&bf)[2][2][2],
                                      f32x4 (&acc)[2][4][2][2]) {
  if (LA) {
#pragma unroll
    for (int i = 0; i < 4; ++i) {
      const int rh = wr * 64 + i * 16 + (lane & 15);
      const char* base = (const char*)R[QM] + rh * 128;
      const int sw = (rh & 7) << 4;
#pragma unroll
      for (int kk = 0; kk < 2; ++kk)
        af[i][kk] = *(const bf16x8*)(base + ((kk * 64 + (lane >> 4) * 16) ^ sw));
    }
  }
  if (LB) {
#pragma unroll
    for (int j = 0; j < 2; ++j) {
      const int rh = wcn * 32 + j * 16 + (lane & 15);
      const char* base = (const char*)R[2 + QN] + rh * 128;
      const int sw = (rh & 7) << 4;
#pragma unroll
      for (int kk = 0; kk < 2; ++kk)
        bf[QN][j][kk] = *(const bf16x8*)(base + ((kk * 64 + (lane >> 4) * 16) ^ sw));
    }
  }
  if (STG) stage_half(sdst, ssrc, tid);
  __builtin_amdgcn_s_barrier();
  asm volatile("s_waitcnt lgkmcnt(0)" ::: "memory");
  __builtin_amdgcn_s_setprio(1);
#pragma unroll
  for (int i = 0; i < 4; ++i)
#pragma unroll
    for (int j = 0; j < 2; ++j)
#pragma unroll
      for (int kk = 0; kk < 2; ++kk)
        acc[QM][i][QN][j] = __builtin_amdgcn_mfma_f32_16x16x32_bf16(
            af[i][kk], bf[QN][j][kk], acc[QM][i][QN][j], 0, 0, 0);
  __builtin_amdgcn_s_setprio(0);
  vmwait<VM>();
  __builtin_amdgcn_s_barrier();
}

__global__ __launch_bounds__(512, 2) void k_gemm(
    const uint16_t* __restrict__ xt, const uint16_t* __restrict__ yt,
    const float* __restrict__ ssx, const float* __restrict__ ssy,
    const float* __restrict__ mvx, const float* __restrict__ mvy,
    uint16_t* __restrict__ S) {
  __shared__ uint16_t lds[2][4][8192];  // 128 KiB
  int flat = blockIdx.x + 9 * blockIdx.y + 81 * blockIdx.z;
  flat = (flat & 7) * 81 + (flat >> 3);  // 648 = 8*81 -> bijective XCD swizzle
  const int nb = flat / 81;
  const int rem = flat - nb * 81;
  const int m0 = (rem % 9) * 256, n0 = (rem / 9) * 256;
  const int tid = threadIdx.x, lane = tid & 63, wid = tid >> 6;
  const int wr = wid >> 2, wcn = wid & 3;
  const uint16_t* Ax = xt + (size_t)nb * PP * CC;
  const uint16_t* By = yt + (size_t)nb * PP * CC;
  const int lswz = (tid & 7) ^ ((tid >> 3) & 7);
  const uint16_t* gAb = Ax + (size_t)(m0 + (tid >> 3)) * CC + lswz * 8;
  const uint16_t* gBb = By + (size_t)(n0 + (tid >> 3)) * CC + lswz * 8;

  f32x4 acc[2][4][2][2];
#pragma unroll
  for (int a = 0; a < 2; ++a)
#pragma unroll
    for (int b = 0; b < 4; ++b)
#pragma unroll
      for (int c = 0; c < 2; ++c)
#pragma unroll
        for (int d = 0; d < 2; ++d) acc[a][b][c][d] = (f32x4){0.f, 0.f, 0.f, 0.f};

  // prologue: as-if ph3,4(kt-2), ph1,2(kt-1), ph3,4(kt-1)
  stage_half(lds[0][0], gAb, tid);              // A0(0)
  stage_half(lds[0][2], gBb, tid);              // B0(0)
  stage_half(lds[0][1], gAb + 128 * CC, tid);   // A1(0)
  stage_half(lds[0][3], gBb + 128 * CC, tid);   // B1(0)
  stage_half(lds[1][0], gAb + 64, tid);         // A0(1)
  stage_half(lds[1][2], gBb + 64, tid);         // B0(1)
  vmwait<8>();                                   // A0(0),B0(0) resident
  __builtin_amdgcn_s_barrier();

  bf16x8 af[4][2], bf[2][2][2];
  for (int kt = 0; kt < 6; ++kt) {
    const int cur = kt & 1;
    const uint16_t(*R)[8192] = lds[cur];
    uint16_t(*Wn)[8192] = lds[cur ^ 1];
    uint16_t(*Wc)[8192] = lds[cur];
    const int ko = (kt + 1) * 64;
    // ph1(0,0): read A0+B0 (cache B0); stage A1(kt+1); vmcnt(6) guards this tile's A1/B1
    phase<0, 0, true, true, true, 6>(R, Wn[1], gAb + 128 * CC + ko, tid, lane, wr, wcn, af, bf, acc);
    // ph2(0,1): read B1 (cache, safe after ph1's vmcnt); stage B1(kt+1)
    phase<0, 1, false, true, true, -1>(R, Wn[3], gBb + 128 * CC + ko, tid, lane, wr, wcn, af, bf, acc);
    // ph3(1,0): read A1, reuse cached B0; stage A0(kt+2)
    phase<1, 0, true, false, true, -1>(R, Wc[0], gAb + ko + 64, tid, lane, wr, wcn, af, bf, acc);
    // ph4(1,1): reuse cached B1 (no ds reads); stage B0(kt+2); vmcnt(8) guards next tile's A0,B0
    phase<1, 1, false, false, true, 8>(R, Wc[2], gBb + ko + 64, tid, lane, wr, wcn, af, bf, acc);
  }
  {  // kt = 6 (cur = 0): last A1/B1 stages; drain ramps 8->4
    const uint16_t(*R)[8192] = lds[0];
    phase<0, 0, true, true, true, 6>(R, lds[1][1], gAb + 128 * CC + 7 * 64, tid, lane, wr, wcn, af, bf, acc);
    phase<0, 1, false, true, true, -1>(R, lds[1][3], gBb + 128 * CC + 7 * 64, tid, lane, wr, wcn, af, bf, acc);
    phase<1, 0, true, false, false, -1>(R, nullptr, nullptr, tid, lane, wr, wcn, af, bf, acc);
    phase<1, 1, false, false, false, 4>(R, nullptr, nullptr, tid, lane, wr, wcn, af, bf, acc);
  }
  {  // kt = 7 (cur = 1): final tile, drain to 0 after ph1
    const uint16_t(*R)[8192] = lds[1];
    phase<0, 0, true, true, false, 0>(R, nullptr, nullptr, tid, lane, wr, wcn, af, bf, acc);
    phase<0, 1, false, true, false, -1>(R, nullptr, nullptr, tid, lane, wr, wcn, af, bf, acc);
    phase<1, 0, true, false, false, -1>(R, nullptr, nullptr, tid, lane, wr, wcn, af, bf, acc);
    phase<1, 1, false, false, false, -1>(R, nullptr, nullptr, tid, lane, wr, wcn, af, bf, acc);
  }

  // epilogue: centering corrections + inverse norms, write bf16 cosine
  const float* rsp = ssx + (size_t)nb * PP + m0;
  const float* csp = ssy + (size_t)nb * PP + n0;
  const float* mvr = mvx + (size_t)nb * PP + m0;
  const float* mvc = mvy + (size_t)nb * PP + n0;
  uint16_t* Sp = S + (size_t)nb * PP * PP;
  float cinv[2][2], cmv[2][2];
#pragma unroll
  for (int qn = 0; qn < 2; ++qn)
#pragma unroll
    for (int j = 0; j < 2; ++j) {
      const int col = qn * 128 + wcn * 32 + j * 16 + (lane & 15);
      const float m = mvc[col];
      cmv[qn][j] = m;
      cinv[qn][j] = 1.0f / fmaxf(sqrtf(csp[col] - 2.0f * m), 1e-12f);
    }
#pragma unroll
  for (int qm = 0; qm < 2; ++qm)
#pragma unroll
    for (int i = 0; i < 4; ++i)
#pragma unroll
      for (int r = 0; r < 4; ++r) {
        const int row = qm * 128 + wr * 64 + i * 16 + (lane >> 4) * 4 + r;
        const float mr = mvr[row];
        const float rinv = 1.0f / fmaxf(sqrtf(rsp[row] - 2.0f * mr), 1e-12f);
        uint16_t* orow = Sp + (size_t)(m0 + row) * PP + n0;
#pragma unroll
        for (int qn = 0; qn < 2; ++qn)
#pragma unroll
          for (int j = 0; j < 2; ++j)
            orow[qn * 128 + wcn * 32 + j * 16 + (lane & 15)] = (uint16_t)f2bf(
                (acc[qm][i][qn][j][r] - mr - cmv[qn][j]) * rinv * cinv[qn][j]);
      }
}

// ------- K4: fused row-stats + colmax; w=exp stored bf16 in LDS (exp once, S read once) -------
__global__ __launch_bounds__(256) void k_rowcol(const uint16_t* __restrict__ S,
                                                int* __restrict__ cxcol) {
  const int pc = blockIdx.x, n = blockIdx.y;  // 24-row chunk, as 2x12-row LDS passes
  __shared__ uint16_t wlds[RCH][PP];          // 55296 B of bf16 w-values
  __shared__ float lri[RCH];
  const int t = threadIdx.x, w = t >> 6, lane = t & 63;
  const size_t Sn = (size_t)n * PP * PP + (size_t)pc * 24 * PP;
  float best0[5], best1[5];
#pragma unroll
  for (int i = 0; i < 5; ++i) { best0[i] = 0.f; best1[i] = 0.f; }
  for (int half = 0; half < 2; ++half) {
    // pass 1: 4 waves x 3 rows; row in-register; w -> LDS bf16; rowsum in f32
    for (int it = 0; it < 3; ++it) {
      const int r = w * 3 + it;  // 0..11
      const uint2* rp = (const uint2*)(S + Sn + (size_t)(half * RCH + r) * PP);
      uint2 u[9];
#pragma unroll
      for (int k = 0; k < 9; ++k) u[k] = rp[lane + k * 64];
      float v[36];
#pragma unroll
      for (int k = 0; k < 9; ++k) {
        v[4 * k + 0] = bf2lo(u[k].x); v[4 * k + 1] = bf2hi(u[k].x);
        v[4 * k + 2] = bf2lo(u[k].y); v[4 * k + 3] = bf2hi(u[k].y);
      }
      float mx = v[0];
#pragma unroll
      for (int k = 1; k < 36; ++k) mx = fmaxf(mx, v[k]);
#pragma unroll
      for (int d = 1; d < 64; d <<= 1) mx = fmaxf(mx, __shfl_xor(mx, d));
      const float sc = 2.0f / (1.0f - mx + EPSF);
      const float b = (EPSF - mx) * sc;
      float s = 0.f;
#pragma unroll
      for (int k = 0; k < 9; ++k) {
        const float w0 = __expf(fmaf(v[4 * k + 0], sc, b));
        const float w1 = __expf(fmaf(v[4 * k + 1], sc, b));
        const float w2 = __expf(fmaf(v[4 * k + 2], sc, b));
        const float w3 = __expf(fmaf(v[4 * k + 3], sc, b));
        s += (w0 + w1) + (w2 + w3);
        uint2 wp;
        wp.x = f2bf(w0) | (f2bf(w1) << 16);
        wp.y = f2bf(w2) | (f2bf(w3) << 16);
        ((uint2*)&wlds[r][0])[lane + k * 64] = wp;
      }
#pragma unroll
      for (int d = 1; d < 64; d <<= 1) s += __shfl_xor(s, d);
      if (lane == 0) lri[r] = 1.0f / s;
    }
    __syncthreads();
    // pass 2: colmax from LDS (mul+max only, no exp); fixed 5-iter for static reg idx
#pragma unroll
    for (int i = 0; i < 5; ++i) {
      const int pi = t + i * 256;
      if (pi < PP / 2) {
        float b0 = best0[i], b1 = best1[i];
#pragma unroll
        for (int r = 0; r < RCH; ++r) {
          const uint32_t u = ((const uint32_t*)&wlds[r][0])[pi];
          const float ri = lri[r];
          b0 = fmaxf(b0, bf2lo(u) * ri);
          b1 = fmaxf(b1, bf2hi(u) * ri);
        }
        best0[i] = b0; best1[i] = b1;
      }
    }
    __syncthreads();  // LDS reuse guard
  }
#pragma unroll
  for (int i = 0; i < 5; ++i) {
    const int pi = t + i * 256;
    if (pi < PP / 2) {
      atomicMax(&cxcol[n * PP + 2 * pi], __float_as_int(best0[i]));
      atomicMax(&cxcol[n * PP + 2 * pi + 1], __float_as_int(best1[i]));
    }
  }
}

// ---------------- K5: per-n colmax sum + final loss (single block, wave w = batch n) ----------------
__global__ __launch_bounds__(512) void k_fin(const int* __restrict__ cxcol,
                                             float* __restrict__ out) {
  __shared__ float red[8];
  const int t = threadIdx.x, w = t >> 6, lane = t & 63;
  float s = 0.f;
  for (int q = lane; q < PP; q += 64) s += __int_as_float(cxcol[w * PP + q]);
#pragma unroll
  for (int d = 1; d < 64; d <<= 1) s += __shfl_xor(s, d);
  if (lane == 0) red[w] = -logf(s * (1.0f / PP) + EPSF);
  __syncthreads();
  if (t == 0) {
    float a = 0.f;
#pragma unroll
    for (int n = 0; n < NB; ++n) a += red[n];
    out[0] = a * (1.0f / NB);
  }
}

extern "C" void kernel_launch(void* const* d_in, const int* in_sizes, int n_in,
                              void* d_out, int out_size, void* d_ws, size_t ws_size,
                              hipStream_t stream) {
  const float* pred = (const float*)d_in[0];
  const float* tgt  = (const float*)d_in[1];
  float* W = (float*)d_ws;
  // workspace layout (float indices)
  float* musum = W + 0;              // 512
  float* ssx   = W + 512;            // 18432
  float* ssy   = W + 18944;          // 18432
  int*   cxcol = (int*)(W + 37376);  // 18432
  float* mvx   = W + 56320;          // 18432
  float* mvy   = W + 74752;          // 18432
  uint16_t* xt = (uint16_t*)(W + 93440);        // 9437184 bf16
  uint16_t* yt = xt + (size_t)NB * PP * CC;     // 9437184 bf16
  uint16_t* S  = yt + (size_t)NB * PP * CC;     // 42467328 bf16

  // zero: musum, ssx, ssy, cxcol (0x0 = 0.0f; all cx values > 0)
  hipMemsetAsync(W, 0, 55808 * sizeof(float), stream);

  k_cast<<<dim3(PP / 64, CC / 64, NB), dim3(256), 0, stream>>>(
      pred, tgt, xt, yt, ssx, ssy, musum);
  k_gemv<<<dim3(288, 2), dim3(256), 0, stream>>>(musum, xt, yt, mvx, mvy);
  k_gemm<<<dim3(9, 9, NB), dim3(512), 0, stream>>>(xt, yt, ssx, ssy, mvx, mvy, S);
  k_rowcol<<<dim3(96, NB), dim3(256), 0, stream>>>(S, cxcol);
  k_fin<<<dim3(1), dim3(512), 0, stream>>>(cxcol, (float*)d_out);
}